// Round 11
// baseline (160.057 us; speedup 1.0000x reference)
//
#include <hip/hip_runtime.h>
#include <hip/hip_bf16.h>
#include <stdint.h>

// Problem constants (GroupedQueryAttention: B=2,S=2048,D=1024,H=16,KVH=4)
#define B_    2
#define S_    2048
#define D_    1024
#define H_    16
#define KVH_  4
#define HD_   64
#define REP_  4
#define BS_   (B_ * S_)        // 4096 tokens
#define KVD_  256
#define QKVS_ 1536             // fused QKV row stride: Q(1024) | K(256) | V(256)
#define NTH_  16               // KV tiles per half (split-KV x2)

typedef unsigned short u16;
typedef short s16x8 __attribute__((ext_vector_type(8)));
typedef float f32x4 __attribute__((ext_vector_type(4)));

typedef const __attribute__((address_space(1))) void* gvp;
typedef __attribute__((address_space(3))) void* lvp;

__device__ __forceinline__ u16 f2b(float f) {  // RNE f32->bf16 (finite inputs)
  uint32_t u = __float_as_uint(f);
  u += 0x7fffu + ((u >> 16) & 1u);
  return (u16)(u >> 16);
}
__device__ __forceinline__ float b2f(u16 v) {
  return __uint_as_float((uint32_t)v << 16);
}

// XOR swizzle for 64-elem-wide bf16 LDS rows (128B = 8 x 16B slots).
__device__ __forceinline__ int swz64(int row, int slot) {
  return slot ^ (row & 7) ^ ((row >> 3) & 7);
}
__device__ __forceinline__ const s16x8* frag64(const u16* base, int row, int slot) {
  return reinterpret_cast<const s16x8*>(base + row * 64 + swz64(row, slot) * 8);
}

// ---------------- fused f32 -> bf16 conversion over 5 segments ----------------
#define N0_ (BS_ * D_ / 4)
#define N1_ (D_ * D_ / 4)
#define N2_ (KVD_ * D_ / 4)
__global__ void cvt5_kernel(const float* __restrict__ s0, const float* __restrict__ s1,
                            const float* __restrict__ s2, const float* __restrict__ s3,
                            const float* __restrict__ s4, u16* __restrict__ dst, int n4tot) {
  for (int i = blockIdx.x * blockDim.x + threadIdx.x; i < n4tot;
       i += gridDim.x * blockDim.x) {
    const float* src;
    int j = i;
    if (j < N0_) src = s0;
    else if ((j -= N0_) < N1_) src = s1;
    else if ((j -= N1_) < N2_) src = s2;
    else if ((j -= N2_) < N2_) src = s3;
    else { j -= N2_; src = s4; }
    const float4 v = reinterpret_cast<const float4*>(src)[j];
    uint2 o;
    o.x = (uint32_t)f2b(v.x) | ((uint32_t)f2b(v.y) << 16);
    o.y = (uint32_t)f2b(v.z) | ((uint32_t)f2b(v.w) << 16);
    reinterpret_cast<uint2*>(dst)[i] = o;
  }
}

// ---------------- bf16 GEMM, C = A(MxK) * B(NxK)^T, 64x128 tile ----------------
// 4 waves (2x2), wave tile 32x64 (2x4 acc). More blocks/CU than 128x128 for
// the small-N shapes here (QKV: 768 blocks=3/CU, out: 512=2/CU).
template <int OUT_BF16>
__global__ __launch_bounds__(256) void gemm64(const u16* __restrict__ A,
                                              const u16* __restrict__ Bw,
                                              void* __restrict__ Cout,
                                              int M, int N, int K) {
  __shared__ u16 As[64 * 32];
  __shared__ u16 Bs[128 * 32];
  const int tid = threadIdx.x;
  const int lane = tid & 63;
  const int wid = tid >> 6;
  const int l16 = lane & 15;
  const int kq = lane >> 4;
  const int bm = blockIdx.y * 64;
  const int bn = blockIdx.x * 128;
  const int wr = (wid >> 1) * 32;
  const int wc = (wid & 1) * 64;

  f32x4 acc[2][4] = {};

  for (int kt = 0; kt < K; kt += 32) {
    __syncthreads();
    {  // A tile: 64x32, 1 load/thread
      const int e = tid * 8;
      const int row = e >> 5;
      const int col = e & 31;
      __builtin_amdgcn_global_load_lds((gvp)(A + (size_t)(bm + row) * K + kt + col),
                                       (lvp)(&As[e]), 16, 0, 0);
    }
#pragma unroll
    for (int i = 0; i < 2; ++i) {  // B tile: 128x32, 2 loads/thread
      const int e = (i * 256 + tid) * 8;
      const int row = e >> 5;
      const int col = e & 31;
      __builtin_amdgcn_global_load_lds((gvp)(Bw + (size_t)(bn + row) * K + kt + col),
                                       (lvp)(&Bs[e]), 16, 0, 0);
    }
    __syncthreads();

    s16x8 af[2], bfr[4];
#pragma unroll
    for (int m = 0; m < 2; ++m)
      af[m] = *reinterpret_cast<const s16x8*>(&As[(wr + m * 16 + l16) * 32 + kq * 8]);
#pragma unroll
    for (int n = 0; n < 4; ++n)
      bfr[n] = *reinterpret_cast<const s16x8*>(&Bs[(wc + n * 16 + l16) * 32 + kq * 8]);
#pragma unroll
    for (int m = 0; m < 2; ++m)
#pragma unroll
      for (int n = 0; n < 4; ++n)
        acc[m][n] = __builtin_amdgcn_mfma_f32_16x16x32_bf16(af[m], bfr[n], acc[m][n], 0, 0, 0);
  }

#pragma unroll
  for (int m = 0; m < 2; ++m) {
    const int row0 = bm + wr + m * 16 + kq * 4;
#pragma unroll
    for (int n = 0; n < 4; ++n) {
      const int col = bn + wc + n * 16 + l16;
#pragma unroll
      for (int r = 0; r < 4; ++r) {
        if (OUT_BF16) {
          ((u16*)Cout)[(size_t)(row0 + r) * N + col] = f2b(acc[m][n][r]);
        } else {
          ((float*)Cout)[(size_t)(row0 + r) * N + col] = acc[m][n][r];
        }
      }
    }
  }
}

// ---------------- V transpose: QKV V-part -> VT[(b*4+g)*64 + d][s] ----------------
__global__ __launch_bounds__(256) void vtrans_kernel(const u16* __restrict__ QKV,
                                                     u16* __restrict__ VT) {
  __shared__ u16 T[64][72];
  const int tid = threadIdx.x;
  const int s0 = blockIdx.x * 64;
  const int bg = blockIdx.y;
  const int b = bg >> 2;
  const int g = bg & 3;
  const int r = tid >> 2;
  const int c0 = (tid & 3) * 16;
  const u16* src = QKV + (size_t)(b * S_ + s0 + r) * QKVS_ + D_ + KVD_ + g * HD_ + c0;
  const uint4 a = reinterpret_cast<const uint4*>(src)[0];
  const uint4 bq = reinterpret_cast<const uint4*>(src)[1];
  *reinterpret_cast<uint4*>(&T[r][c0]) = a;
  *reinterpret_cast<uint4*>(&T[r][c0 + 8]) = bq;
  __syncthreads();
  const int d = tid >> 2;
  u16 tmp[16];
#pragma unroll
  for (int j = 0; j < 16; ++j) tmp[j] = T[c0 + j][d];
  u16* dst = VT + ((size_t)bg * 64 + d) * S_ + s0 + c0;
  *reinterpret_cast<uint4*>(dst) = *reinterpret_cast<const uint4*>(&tmp[0]);
  *reinterpret_cast<uint4*>(dst + 8) = *reinterpret_cast<const uint4*>(&tmp[8]);
}

// ---------------- flash attention (GQA), split-KV x2 ----------------
// grid (S/32, B*KVH, 2). Round-10 verified tile loop; blockIdx.z selects a
// half of the KV range (16 tiles). Epilogue writes l-normalized partial O
// (bf16) + per-(q,h) (m,l) for the merge kernel. 1024 blocks = 4/CU.
__global__ __launch_bounds__(256) void attn_kernel(const u16* __restrict__ QKV,
                                                   const u16* __restrict__ VT,
                                                   const int* __restrict__ mask,
                                                   u16* __restrict__ Opart,
                                                   float2* __restrict__ ML) {
  __shared__ u16 Ks[2][64 * 64];
  __shared__ u16 Vt[2][64 * 64];
  __shared__ float smask[2][64];

  const int tid = threadIdx.x;
  const int lane = tid & 63;
  const int wid = tid >> 6;
  const int l16 = lane & 15;
  const int kq = lane >> 4;
  const int bg = blockIdx.y;
  const int b = bg >> 2;
  const int g = bg & 3;
  const int h = g * REP_ + wid;
  const int q0 = blockIdx.x * 32;
  const int half = blockIdx.z;
  const int kvb = half * (S_ / 2);     // KV range base for this block
  const u16* kv_base = QKV + (size_t)b * S_ * QKVS_ + D_ + g * HD_;
  const u16* vt_base = VT + (size_t)bg * 64 * S_;

  auto kstage = [&](int buf, int kv0) {
#pragma unroll
    for (int i = 0; i < 2; ++i) {
      const int e = (i * 256 + tid) * 8;
      const int row = e >> 6;
      const int slot = (e >> 3) & 7;
      __builtin_amdgcn_global_load_lds(
          (gvp)(kv_base + (size_t)(kv0 + row) * QKVS_ + swz64(row, slot) * 8),
          (lvp)(&Ks[buf][e]), 16, 0, 0);
    }
  };
  auto vstage = [&](int buf, int kv0) {
#pragma unroll
    for (int i = 0; i < 2; ++i) {
      const int e = (i * 256 + tid) * 8;
      const int row = e >> 6;
      const int slot = (e >> 3) & 7;
      __builtin_amdgcn_global_load_lds(
          (gvp)(vt_base + (size_t)row * S_ + kv0 + swz64(row, slot) * 8),
          (lvp)(&Vt[buf][e]), 16, 0, 0);
    }
  };

  s16x8 qf[2][2];
#pragma unroll
  for (int g2 = 0; g2 < 2; ++g2) {
    const u16* qp = QKV + (size_t)(b * S_ + q0 + g2 * 16 + l16) * QKVS_ + h * HD_ + kq * 8;
    qf[g2][0] = *reinterpret_cast<const s16x8*>(qp);
    qf[g2][1] = *reinterpret_cast<const s16x8*>(qp + 32);
  }

  kstage(0, kvb);
  vstage(0, kvb);
  {
    int mr = 0;
    if (tid < 64) mr = mask[b * S_ + kvb + tid];
    if (tid < 64) smask[0][tid] = mr ? 0.f : -1e30f;
  }

  float m_run[2] = {-1e30f, -1e30f}, l_run[2] = {0.f, 0.f};
  f32x4 acc[2][4] = {};
  const float Cs = 0.18033688011112042f;  // SCALE * log2(e)
  int cur = 0;

  for (int t = 0; t < NTH_; ++t) {
    __syncthreads();
    const bool pfch = (t + 1 < NTH_);
    int mreg = 0;
    if (pfch) {
      kstage(cur ^ 1, kvb + (t + 1) * 64);
      vstage(cur ^ 1, kvb + (t + 1) * 64);
      if (tid < 64) mreg = mask[b * S_ + kvb + (t + 1) * 64 + tid];
    }

    const u16* ks = &Ks[cur][0];
    const u16* vt = &Vt[cur][0];
    const float* sm = &smask[cur][0];

    f32x4 sc[2][4];
#pragma unroll
    for (int n = 0; n < 4; ++n) {
      f32x4 s0 = {0.f, 0.f, 0.f, 0.f};
      f32x4 s1 = {0.f, 0.f, 0.f, 0.f};
#pragma unroll
      for (int c = 0; c < 2; ++c) {
        const s16x8 kf = *frag64(ks, n * 16 + l16, c * 4 + kq);
        s0 = __builtin_amdgcn_mfma_f32_16x16x32_bf16(kf, qf[0][c], s0, 0, 0, 0);
        s1 = __builtin_amdgcn_mfma_f32_16x16x32_bf16(kf, qf[1][c], s1, 0, 0, 0);
      }
      sc[0][n] = s0;
      sc[1][n] = s1;
    }

    f32x4 mk[4];
#pragma unroll
    for (int n = 0; n < 4; ++n)
      mk[n] = *reinterpret_cast<const f32x4*>(&sm[n * 16 + kq * 4]);

    union { uint32_t u[4]; s16x8 v; } pf[2][2];
#pragma unroll
    for (int g2 = 0; g2 < 2; ++g2) {
      float tm = -1e30f;
#pragma unroll
      for (int n = 0; n < 4; ++n)
#pragma unroll
        for (int r = 0; r < 4; ++r) {
          sc[g2][n][r] = sc[g2][n][r] * Cs + mk[n][r];
          tm = fmaxf(tm, sc[g2][n][r]);
        }
      tm = fmaxf(tm, __shfl_xor(tm, 16));
      tm = fmaxf(tm, __shfl_xor(tm, 32));

      if (!__all(tm <= m_run[g2] + 8.0f)) {
        const float mnew = fmaxf(m_run[g2], tm);
        const float fac = exp2f(m_run[g2] - mnew);
        m_run[g2] = mnew;
        l_run[g2] *= fac;
#pragma unroll
        for (int m = 0; m < 4; ++m)
#pragma unroll
          for (int r = 0; r < 4; ++r) acc[g2][m][r] *= fac;
      }

      float rs = 0.f;
#pragma unroll
      for (int n = 0; n < 4; ++n)
#pragma unroll
        for (int r = 0; r < 4; ++r) {
          const float p = exp2f(sc[g2][n][r] - m_run[g2]);
          sc[g2][n][r] = p;
          rs += p;
        }
      rs += __shfl_xor(rs, 16);
      rs += __shfl_xor(rs, 32);
      l_run[g2] += rs;

      uint32_t pk[4][2];
#pragma unroll
      for (int n = 0; n < 4; ++n) {
        asm("v_cvt_pk_bf16_f32 %0, %1, %2" : "=v"(pk[n][0]) : "v"(sc[g2][n][0]), "v"(sc[g2][n][1]));
        asm("v_cvt_pk_bf16_f32 %0, %1, %2" : "=v"(pk[n][1]) : "v"(sc[g2][n][2]), "v"(sc[g2][n][3]));
      }
      const int srcA = ((kq & 1) * 2) * 16 + l16;
      const int srcB = srcA + 16;
#pragma unroll
      for (int c = 0; c < 2; ++c)
#pragma unroll
        for (int w = 0; w < 4; ++w) {
          const int src = (w < 2) ? srcA : srcB;
          const uint32_t lo = __shfl(pk[2 * c][w & 1], src);
          const uint32_t hi = __shfl(pk[2 * c + 1][w & 1], src);
          pf[g2][c].u[w] = (kq & 2) ? hi : lo;
        }
    }

#pragma unroll
    for (int m = 0; m < 4; ++m) {
      const s16x8 vf0 = *frag64(vt, m * 16 + l16, kq);
      const s16x8 vf1 = *frag64(vt, m * 16 + l16, 4 + kq);
      acc[0][m] = __builtin_amdgcn_mfma_f32_16x16x32_bf16(vf0, pf[0][0].v, acc[0][m], 0, 0, 0);
      acc[0][m] = __builtin_amdgcn_mfma_f32_16x16x32_bf16(vf1, pf[0][1].v, acc[0][m], 0, 0, 0);
      acc[1][m] = __builtin_amdgcn_mfma_f32_16x16x32_bf16(vf0, pf[1][0].v, acc[1][m], 0, 0, 0);
      acc[1][m] = __builtin_amdgcn_mfma_f32_16x16x32_bf16(vf1, pf[1][1].v, acc[1][m], 0, 0, 0);
    }

    if (pfch && tid < 64) smask[cur ^ 1][tid] = mreg ? 0.f : -1e30f;
    cur ^= 1;
  }

  // epilogue: l-normalized partial O + (m,l) for merge
#pragma unroll
  for (int g2 = 0; g2 < 2; ++g2) {
    const float rl = (l_run[g2] > 0.f) ? 1.0f / l_run[g2] : 0.f;
    u16* op = Opart + (size_t)(half * BS_ + b * S_ + q0 + g2 * 16 + l16) * D_ +
              h * HD_ + kq * 4;
#pragma unroll
    for (int m = 0; m < 4; ++m) {
      uint2 o;
      o.x = (uint32_t)f2b(acc[g2][m][0] * rl) | ((uint32_t)f2b(acc[g2][m][1] * rl) << 16);
      o.y = (uint32_t)f2b(acc[g2][m][2] * rl) | ((uint32_t)f2b(acc[g2][m][3] * rl) << 16);
      *reinterpret_cast<uint2*>(op + m * 16) = o;
    }
    if (kq == 0) {
      ML[((size_t)(half * B_ + b) * H_ + h) * S_ + q0 + g2 * 16 + l16] =
          make_float2(m_run[g2], l_run[g2]);
    }
  }
}

// ---------------- merge the two KV-half partials ----------------
__global__ __launch_bounds__(256) void merge_kernel(const u16* __restrict__ Opart,
                                                    const float2* __restrict__ ML,
                                                    u16* __restrict__ AO) {
  const int idx = blockIdx.x * 256 + threadIdx.x;   // BS_*128 total
  const int row = idx >> 7;
  const int c8 = (idx & 127) * 8;
  const int b = row >> 11;             // / S_
  const int s = row & (S_ - 1);
  const int h = c8 >> 6;
  const float2 a = ML[((size_t)b * H_ + h) * S_ + s];
  const float2 c = ML[((size_t)(B_ + b) * H_ + h) * S_ + s];
  const float m = fmaxf(a.x, c.x);
  const float w0 = a.y * exp2f(a.x - m);
  const float w1 = c.y * exp2f(c.x - m);
  const float tot = w0 + w1;
  const float f0 = (tot > 0.f) ? w0 / tot : 0.f;
  const float f1 = (tot > 0.f) ? w1 / tot : 0.f;
  const uint4 o0 = *reinterpret_cast<const uint4*>(Opart + (size_t)row * D_ + c8);
  const uint4 o1 = *reinterpret_cast<const uint4*>(Opart + (size_t)(BS_ + row) * D_ + c8);
  const uint32_t* p0 = reinterpret_cast<const uint32_t*>(&o0);
  const uint32_t* p1 = reinterpret_cast<const uint32_t*>(&o1);
  uint32_t r[4];
#pragma unroll
  for (int j = 0; j < 4; ++j) {
    const float lo = b2f((u16)(p0[j] & 0xffffu)) * f0 + b2f((u16)(p1[j] & 0xffffu)) * f1;
    const float hi = b2f((u16)(p0[j] >> 16)) * f0 + b2f((u16)(p1[j] >> 16)) * f1;
    r[j] = (uint32_t)f2b(lo) | ((uint32_t)f2b(hi) << 16);
  }
  *reinterpret_cast<uint4*>(AO + (size_t)row * D_ + c8) = *reinterpret_cast<uint4*>(&r[0]);
}

// ---------------- launch ----------------
extern "C" void kernel_launch(void* const* d_in, const int* in_sizes, int n_in,
                              void* d_out, int out_size, void* d_ws, size_t ws_size,
                              hipStream_t stream) {
  const float* x = (const float*)d_in[0];
  const int* mask = (const int*)d_in[1];
  const float* Wq = (const float*)d_in[2];
  const float* Wk = (const float*)d_in[3];
  const float* Wv = (const float*)d_in[4];
  const float* Wo = (const float*)d_in[5];

  char* w = (char*)d_ws;
  u16* xb = (u16*)w;    w += (size_t)BS_ * D_ * 2;     // contiguous cvt dst
  u16* Wqkvb = (u16*)w; w += (size_t)QKVS_ * D_ * 2;
  u16* Wob = (u16*)w;   w += (size_t)D_ * D_ * 2;
  u16* QKVw = (u16*)w;  w += (size_t)BS_ * QKVS_ * 2;
  u16* VTw = (u16*)w;   w += (size_t)B_ * KVH_ * HD_ * S_ * 2;
  u16* AOw = (u16*)w;   w += (size_t)BS_ * D_ * 2;
  u16* Opart = (u16*)w; w += (size_t)2 * BS_ * D_ * 2;   // [half][BS][D]
  float2* MLw = (float2*)w; w += (size_t)2 * B_ * H_ * S_ * sizeof(float2);

  const int n4tot = (BS_ * D_ + QKVS_ * D_ + D_ * D_) / 4;
  cvt5_kernel<<<dim3(2048), dim3(256), 0, stream>>>(x, Wq, Wk, Wv, Wo, xb, n4tot);

  // fused QKV projection: (4096 x 1536), 64x128 tiles -> 768 blocks (3/CU)
  gemm64<1><<<dim3(QKVS_ / 128, BS_ / 64), dim3(256), 0, stream>>>(xb, Wqkvb, QKVw, BS_, QKVS_, D_);
  // transpose V for direct LDS staging
  vtrans_kernel<<<dim3(S_ / 64, B_ * KVH_), dim3(256), 0, stream>>>(QKVw, VTw);
  // attention, split-KV x2: (64, 8, 2) = 1024 blocks (4/CU)
  attn_kernel<<<dim3(S_ / 32, B_ * KVH_, 2), dim3(256), 0, stream>>>(QKVw, VTw, mask, Opart, MLw);
  // merge halves -> AOw
  merge_kernel<<<dim3(BS_ * 128 / 256), dim3(256), 0, stream>>>(Opart, MLw, AOw);
  // output projection -> fp32 d_out, 64x128 tiles -> 512 blocks (2/CU)
  gemm64<0><<<dim3(D_ / 128, BS_ / 64), dim3(256), 0, stream>>>(AOw, Wob, (float*)d_out, BS_, D_, D_);
}